// Round 4
// baseline (291.356 us; speedup 1.0000x reference)
//
#include <hip/hip_runtime.h>

// NARX RNN. Inputs fp32, compute bf16 MFMA 16x16x32, OUTPUT FP32.
// All GEMMs computed transposed (Ht[n][m] = W^T . act^T) so that:
//   - weight frags (A-operand) are hoisted to registers once per block
//   - MFMA C/D output (lane holds col=m, 4 consecutive n') packs into one
//     b64 LDS store at act[m][n'..n'+3]
//   - that same [m][hid] row-major LDS layout is exactly the B-fragment
//     read pattern (lane&15 = m, k = quad*8+j contiguous) -> ds_read_b128
// LDS row stride 72 shorts (144B): b128 frag reads are uniform 8 acc/bank.

#define NTT   512
#define NG    2048
#define NXF   16
#define HIDN  64
#define DLAG  4
#define TOUTN 508
#define GBLK  128   // g rows per block (4 waves x 32)
#define TTB   4     // tt values per block
#define STR   72    // LDS row stride in shorts

typedef short  short8 __attribute__((ext_vector_type(8)));
typedef float  f32x4  __attribute__((ext_vector_type(4)));
typedef unsigned short u16x4 __attribute__((ext_vector_type(4)));

__device__ __forceinline__ float bf2f(int u) {
    return __uint_as_float(((unsigned int)(u & 0xffff)) << 16);
}
__device__ __forceinline__ unsigned short f2bf(float f) {  // RTNE
    unsigned int u = __float_as_uint(f);
    u += 0x7fffu + ((u >> 16) & 1u);
    return (unsigned short)(u >> 16);
}
__device__ __forceinline__ float tanh_fast(float x) {
    // tanh(x) = 1 - 2/(exp2(x*2*log2e)+1); saturates correctly at +/-inf
    float e = exp2f(x * 2.8853900817779268f);
    return 1.0f - 2.0f * __builtin_amdgcn_rcpf(e + 1.0f);
}

__global__ __launch_bounds__(256, 2)
void narx_kernel(const float* __restrict__ x,
                 const float* __restrict__ Win,
                 const float* __restrict__ bin_g,
                 const float* __restrict__ Wxh,
                 const float* __restrict__ Whh,
                 const float* __restrict__ bh_g,
                 const float* __restrict__ Wout,
                 const float* __restrict__ bout_g,
                 float* __restrict__ out)
{
    __shared__ unsigned short s_wT[HIDN * STR];  // weight staging (transposed, bf16)
    __shared__ unsigned short s_u[GBLK * STR];   // u activations, [m][hid], bf16
    __shared__ unsigned short s_h[GBLK * STR];   // h activations, [m][hid], bf16

    const int tid   = threadIdx.x;
    const int w     = tid >> 6;
    const int lane  = tid & 63;
    const int lm    = lane & 15;   // tile-local m (B/C col) or n' (A row)
    const int q     = lane >> 4;   // quad
    const int G0    = blockIdx.x * GBLK;
    const int tt0   = blockIdx.y * TTB;
    const int wrow0 = w * 32;      // this wave's first row in block

    // zero the t<DLAG head of the output (poisoned before every launch)
    if (blockIdx.y == 0 && tid < GBLK) {
        #pragma unroll
        for (int t2 = 0; t2 < DLAG; ++t2)
            out[t2 * NG + G0 + tid] = 0.0f;
    }

    // ---- stage weights transposed (fp32 -> bf16), hoist A-frags to regs ----
    short8 wxhf[4][2], whhf[4][2], winf[4];
    {   // Wxh^T : s_wT[n*STR+k] = bf16(Wxh[k*64+n])
        int k = tid >> 2, n0 = (tid & 3) * 16;
        const float* src = Wxh + k * HIDN + n0;
        #pragma unroll
        for (int i = 0; i < 16; ++i) s_wT[(n0 + i) * STR + k] = f2bf(src[i]);
    }
    __syncthreads();
    #pragma unroll
    for (int tn = 0; tn < 4; ++tn)
        #pragma unroll
        for (int kk = 0; kk < 2; ++kk)
            wxhf[tn][kk] = *(const short8*)&s_wT[(tn*16 + lm) * STR + kk*32 + q*8];
    __syncthreads();
    {   // Whh^T
        int k = tid >> 2, n0 = (tid & 3) * 16;
        const float* src = Whh + k * HIDN + n0;
        #pragma unroll
        for (int i = 0; i < 16; ++i) s_wT[(n0 + i) * STR + k] = f2bf(src[i]);
    }
    __syncthreads();
    #pragma unroll
    for (int tn = 0; tn < 4; ++tn)
        #pragma unroll
        for (int kk = 0; kk < 2; ++kk)
            whhf[tn][kk] = *(const short8*)&s_wT[(tn*16 + lm) * STR + kk*32 + q*8];
    __syncthreads();
    {   // Win^T (16 x 64 -> [n][k], k<16)
        int k = tid >> 4, n0 = (tid & 15) * 4;
        const float* src = Win + k * HIDN + n0;
        #pragma unroll
        for (int i = 0; i < 4; ++i) s_wT[(n0 + i) * STR + k] = f2bf(src[i]);
    }
    __syncthreads();
    #pragma unroll
    for (int tn = 0; tn < 4; ++tn) {
        short8 z = {0,0,0,0,0,0,0,0};
        if (q < 2) z = *(const short8*)&s_wT[(tn*16 + lm) * STR + q*8];
        winf[tn] = z;   // quads 2,3 are K=16..31 zero-padding
    }

    // biases, fp32 exact, per-lane: index n' = tj*16 + q*4 + r
    float binf[4][4], bhf[4][4];
    #pragma unroll
    for (int tj = 0; tj < 4; ++tj) {
        f32x4 b4 = *(const f32x4*)&bin_g[tj*16 + q*4];
        f32x4 h4 = *(const f32x4*)&bh_g[tj*16 + q*4];
        #pragma unroll
        for (int r = 0; r < 4; ++r) { binf[tj][r] = b4[r]; bhf[tj][r] = h4[r]; }
    }
    const float boutf = bout_g[0];
    __syncthreads();

    for (int ti = 0; ti < TTB; ++ti) {
        const int tt = tt0 + ti;

        for (int d = 0; d < DLAG; ++d) {
            // ---- u^T = Win^T . x^T  (+b_in, relu) ----
            f32x4 ua[4][2];
            #pragma unroll
            for (int tj = 0; tj < 4; ++tj)
                #pragma unroll
                for (int mt = 0; mt < 2; ++mt) {
                    f32x4 a;
                    a[0]=binf[tj][0]; a[1]=binf[tj][1]; a[2]=binf[tj][2]; a[3]=binf[tj][3];
                    ua[tj][mt] = a;
                }
            short8 xf[2];
            #pragma unroll
            for (int mt = 0; mt < 2; ++mt) {
                short8 z = {0,0,0,0,0,0,0,0};
                if (q < 2) {  // k = q*8.. <16 real, quads 2,3 zero-pad
                    const float* px =
                        x + ((size_t)(tt + d) * NG + (G0 + wrow0 + mt*16 + lm)) * NXF + q*8;
                    f32x4 a = *(const f32x4*)px;        // 32B coalesced, row-major [g][i]
                    f32x4 b = *(const f32x4*)(px + 4);
                    z[0]=(short)f2bf(a[0]); z[1]=(short)f2bf(a[1]);
                    z[2]=(short)f2bf(a[2]); z[3]=(short)f2bf(a[3]);
                    z[4]=(short)f2bf(b[0]); z[5]=(short)f2bf(b[1]);
                    z[6]=(short)f2bf(b[2]); z[7]=(short)f2bf(b[3]);
                }
                xf[mt] = z;
            }
            #pragma unroll
            for (int tj = 0; tj < 4; ++tj)
                #pragma unroll
                for (int mt = 0; mt < 2; ++mt)
                    ua[tj][mt] = __builtin_amdgcn_mfma_f32_16x16x32_bf16(
                        winf[tj], xf[mt], ua[tj][mt], 0, 0, 0);
            // relu + cvt + pack: lane holds u[n'=tj*16+q*4+r][m], write act[m][n']
            #pragma unroll
            for (int tj = 0; tj < 4; ++tj)
                #pragma unroll
                for (int mt = 0; mt < 2; ++mt) {
                    u16x4 p;
                    #pragma unroll
                    for (int r = 0; r < 4; ++r) p[r] = f2bf(fmaxf(ua[tj][mt][r], 0.0f));
                    *(u16x4*)&s_u[(wrow0 + mt*16 + lm) * STR + tj*16 + q*4] = p;
                }
            __syncthreads();

            // ---- h^T = Wxh^T.u^T + Whh^T.h^T (+b_h, tanh) ----
            f32x4 ha[4][2];
            #pragma unroll
            for (int tn = 0; tn < 4; ++tn)
                #pragma unroll
                for (int mt = 0; mt < 2; ++mt) {
                    f32x4 a;
                    a[0]=bhf[tn][0]; a[1]=bhf[tn][1]; a[2]=bhf[tn][2]; a[3]=bhf[tn][3];
                    ha[tn][mt] = a;
                }
            #pragma unroll
            for (int kk = 0; kk < 2; ++kk) {
                short8 uf[2], hf[2];
                #pragma unroll
                for (int mt = 0; mt < 2; ++mt)
                    uf[mt] = *(const short8*)&s_u[(wrow0 + mt*16 + lm) * STR + kk*32 + q*8];
                if (d > 0) {
                    #pragma unroll
                    for (int mt = 0; mt < 2; ++mt)
                        hf[mt] = *(const short8*)&s_h[(wrow0 + mt*16 + lm) * STR + kk*32 + q*8];
                }
                #pragma unroll
                for (int tn = 0; tn < 4; ++tn)
                    #pragma unroll
                    for (int mt = 0; mt < 2; ++mt) {
                        ha[tn][mt] = __builtin_amdgcn_mfma_f32_16x16x32_bf16(
                            wxhf[tn][kk], uf[mt], ha[tn][mt], 0, 0, 0);
                        if (d > 0)
                            ha[tn][mt] = __builtin_amdgcn_mfma_f32_16x16x32_bf16(
                                whhf[tn][kk], hf[mt], ha[tn][mt], 0, 0, 0);
                    }
            }
            __syncthreads();
            #pragma unroll
            for (int tn = 0; tn < 4; ++tn)
                #pragma unroll
                for (int mt = 0; mt < 2; ++mt) {
                    u16x4 p;
                    #pragma unroll
                    for (int r = 0; r < 4; ++r) p[r] = f2bf(tanh_fast(ha[tn][mt][r]));
                    *(u16x4*)&s_h[(wrow0 + mt*16 + lm) * STR + tn*16 + q*4] = p;
                }
            __syncthreads();
        }

        // ---- y = h @ Wout + bout : 2 lanes per row, fp32 Wout, FP32 store ----
        {
            int row = lane >> 1, half = lane & 1;
            const unsigned short* hr = &s_h[(wrow0 + row) * STR + half*32];
            const float* wo = Wout + half*32;
            float acc = 0.f;
            #pragma unroll
            for (int jb = 0; jb < 4; ++jb) {
                u16x4 h0 = *(const u16x4*)&hr[jb*8];
                u16x4 h1 = *(const u16x4*)&hr[jb*8 + 4];
                f32x4 w0 = *(const f32x4*)&wo[jb*8];
                f32x4 w1 = *(const f32x4*)&wo[jb*8 + 4];
                #pragma unroll
                for (int e = 0; e < 4; ++e)
                    acc += bf2f(h0[e]) * w0[e] + bf2f(h1[e]) * w1[e];
            }
            acc += __shfl_xor(acc, 1, 64);
            if (half == 0)
                out[(size_t)(tt + DLAG) * NG + G0 + wrow0 + row] = acc + boutf;
        }
        __syncthreads();
    }
}

extern "C" void kernel_launch(void* const* d_in, const int* in_sizes, int n_in,
                              void* d_out, int out_size, void* d_ws, size_t ws_size,
                              hipStream_t stream) {
    const float* x    = (const float*)d_in[0];
    const float* Win  = (const float*)d_in[1];
    const float* bin  = (const float*)d_in[2];
    const float* Wxh  = (const float*)d_in[3];
    const float* Whh  = (const float*)d_in[4];
    const float* bh   = (const float*)d_in[5];
    const float* Wout = (const float*)d_in[6];
    const float* bout = (const float*)d_in[7];
    float* out = (float*)d_out;

    dim3 grid(NG / GBLK, TOUTN / TTB);  // (16, 127)
    narx_kernel<<<grid, dim3(256), 0, stream>>>(x, Win, bin, Wxh, Whh, bh, Wout, bout, out);
}

// Round 5
// 268.727 us; speedup vs baseline: 1.0842x; 1.0842x over previous
//
#include <hip/hip_runtime.h>
#include <hip/hip_bf16.h>

// NARX RNN. Inputs fp32, compute bf16 MFMA 16x16x32, output fp32.
// Transposed GEMMs (Ht[n][m] = W^T . act^T): weight A-frags hoisted to regs,
// C/D output packs straight into the [m][hid] LDS layout the next B-frag
// read wants. LDS row stride 72 shorts (144B), rows 16B-aligned for b128.
// Main-loop LDS is wave-private (each wave touches only its 32 rows) ->
// NO __syncthreads in the hot loop; barriers only around weight staging.
// All f32->bf16 via packed cvt (v_cvt_pk_bf16_f32 on gfx950).

#define NTT   512
#define NG    2048
#define NXF   16
#define HIDN  64
#define DLAG  4
#define TOUTN 508
#define GBLK  128   // g rows per block (4 waves x 32)
#define TTB   4     // tt values per block
#define STR   72    // LDS row stride in shorts

typedef short  short8 __attribute__((ext_vector_type(8)));
typedef float  f32x4  __attribute__((ext_vector_type(4)));
typedef int    i32x4  __attribute__((ext_vector_type(4)));
typedef unsigned int u32x2 __attribute__((ext_vector_type(2)));

__device__ __forceinline__ unsigned short f2bf(float f) {  // RTNE (init path only)
    unsigned int u = __float_as_uint(f);
    u += 0x7fffu + ((u >> 16) & 1u);
    return (unsigned short)(u >> 16);
}
__device__ __forceinline__ float bf2f(int u) {
    return __uint_as_float(((unsigned int)(u & 0xffff)) << 16);
}
__device__ __forceinline__ unsigned int pk2bf(float a, float b) {  // [lo=a, hi=b]
    union { __hip_bfloat162 h2; unsigned int u; } c;
    c.h2 = __float22bfloat162_rn(float2{a, b});
    return c.u;
}
__device__ __forceinline__ float tanh_fast(float x) {
    float e = exp2f(x * 2.8853900817779268f);
    return 1.0f - 2.0f * __builtin_amdgcn_rcpf(e + 1.0f);
}

__global__ __launch_bounds__(256, 2)
void narx_kernel(const float* __restrict__ x,
                 const float* __restrict__ Win,
                 const float* __restrict__ bin_g,
                 const float* __restrict__ Wxh,
                 const float* __restrict__ Whh,
                 const float* __restrict__ bh_g,
                 const float* __restrict__ Wout,
                 const float* __restrict__ bout_g,
                 float* __restrict__ out)
{
    __shared__ unsigned short s_u[GBLK * STR];   // u acts; doubles as weight staging in init
    __shared__ unsigned short s_h[GBLK * STR];   // h acts
    unsigned short* s_wT = s_u;                  // init-phase alias (4600 < 9216 shorts)

    const int tid   = threadIdx.x;
    const int w     = tid >> 6;
    const int lane  = tid & 63;
    const int lm    = lane & 15;
    const int q     = lane >> 4;
    const int G0    = blockIdx.x * GBLK;
    const int tt0   = blockIdx.y * TTB;
    const int wrow0 = w * 32;

    // zero the t<DLAG head of the output (poisoned before every launch)
    if (blockIdx.y == 0 && tid < GBLK) {
        #pragma unroll
        for (int t2 = 0; t2 < DLAG; ++t2)
            out[t2 * NG + G0 + tid] = 0.0f;
    }

    // ---- stage weights transposed (fp32 -> bf16), hoist A-frags to regs ----
    short8 wxhf[4][2], whhf[4][2], winf[4];
    {   // Wxh^T : s_wT[n*STR+k] = bf16(Wxh[k*64+n])
        int k = tid >> 2, n0 = (tid & 3) * 16;
        const float* src = Wxh + k * HIDN + n0;
        #pragma unroll
        for (int i = 0; i < 16; ++i) s_wT[(n0 + i) * STR + k] = f2bf(src[i]);
    }
    __syncthreads();
    #pragma unroll
    for (int tn = 0; tn < 4; ++tn)
        #pragma unroll
        for (int kk = 0; kk < 2; ++kk)
            wxhf[tn][kk] = *(const short8*)&s_wT[(tn*16 + lm) * STR + kk*32 + q*8];
    __syncthreads();
    {   // Whh^T
        int k = tid >> 2, n0 = (tid & 3) * 16;
        const float* src = Whh + k * HIDN + n0;
        #pragma unroll
        for (int i = 0; i < 16; ++i) s_wT[(n0 + i) * STR + k] = f2bf(src[i]);
    }
    __syncthreads();
    #pragma unroll
    for (int tn = 0; tn < 4; ++tn)
        #pragma unroll
        for (int kk = 0; kk < 2; ++kk)
            whhf[tn][kk] = *(const short8*)&s_wT[(tn*16 + lm) * STR + kk*32 + q*8];
    __syncthreads();
    {   // Win^T (16 x 64 -> [n][k], k<16)
        int k = tid >> 4, n0 = (tid & 15) * 4;
        const float* src = Win + k * HIDN + n0;
        #pragma unroll
        for (int i = 0; i < 4; ++i) s_wT[(n0 + i) * STR + k] = f2bf(src[i]);
    }
    __syncthreads();
    #pragma unroll
    for (int tn = 0; tn < 4; ++tn) {
        short8 z = {0,0,0,0,0,0,0,0};
        if (q < 2) z = *(const short8*)&s_wT[(tn*16 + lm) * STR + q*8];
        winf[tn] = z;   // quads 2,3 are K=16..31 zero-padding
    }

    // biases, fp32 exact, per-lane: index n' = tj*16 + q*4 + r
    float binf[4][4], bhf[4][4];
    #pragma unroll
    for (int tj = 0; tj < 4; ++tj) {
        f32x4 b4 = *(const f32x4*)&bin_g[tj*16 + q*4];
        f32x4 h4 = *(const f32x4*)&bh_g[tj*16 + q*4];
        #pragma unroll
        for (int r = 0; r < 4; ++r) { binf[tj][r] = b4[r]; bhf[tj][r] = h4[r]; }
    }
    const float boutf = bout_g[0];
    __syncthreads();   // last init barrier: staging alias dies, s_u becomes act buffer

    for (int ti = 0; ti < TTB; ++ti) {
        const int tt = tt0 + ti;

        for (int d = 0; d < DLAG; ++d) {
            // ---- u^T = Win^T . x^T  (+b_in, relu) ----
            f32x4 ua[4][2];
            #pragma unroll
            for (int tj = 0; tj < 4; ++tj)
                #pragma unroll
                for (int mt = 0; mt < 2; ++mt) {
                    f32x4 a;
                    a[0]=binf[tj][0]; a[1]=binf[tj][1]; a[2]=binf[tj][2]; a[3]=binf[tj][3];
                    ua[tj][mt] = a;
                }
            short8 xf[2];
            #pragma unroll
            for (int mt = 0; mt < 2; ++mt) {
                short8 z = {0,0,0,0,0,0,0,0};
                if (q < 2) {  // k = q*8.. <16 real, quads 2,3 zero-pad
                    const float* px =
                        x + ((size_t)(tt + d) * NG + (G0 + wrow0 + mt*16 + lm)) * NXF + q*8;
                    f32x4 a = *(const f32x4*)px;
                    f32x4 b = *(const f32x4*)(px + 4);
                    i32x4 xi;
                    xi[0] = (int)pk2bf(a[0], a[1]);
                    xi[1] = (int)pk2bf(a[2], a[3]);
                    xi[2] = (int)pk2bf(b[0], b[1]);
                    xi[3] = (int)pk2bf(b[2], b[3]);
                    z = __builtin_bit_cast(short8, xi);
                }
                xf[mt] = z;
            }
            #pragma unroll
            for (int tj = 0; tj < 4; ++tj)
                #pragma unroll
                for (int mt = 0; mt < 2; ++mt)
                    ua[tj][mt] = __builtin_amdgcn_mfma_f32_16x16x32_bf16(
                        winf[tj], xf[mt], ua[tj][mt], 0, 0, 0);
            // relu + packed cvt: lane holds u[n'=tj*16+q*4+r][m=lm], store act[m][n']
            #pragma unroll
            for (int tj = 0; tj < 4; ++tj)
                #pragma unroll
                for (int mt = 0; mt < 2; ++mt) {
                    u32x2 p;
                    p[0] = pk2bf(fmaxf(ua[tj][mt][0], 0.f), fmaxf(ua[tj][mt][1], 0.f));
                    p[1] = pk2bf(fmaxf(ua[tj][mt][2], 0.f), fmaxf(ua[tj][mt][3], 0.f));
                    *(u32x2*)&s_u[(wrow0 + mt*16 + lm) * STR + tj*16 + q*4] = p;
                }
            // (no barrier: s_u rows wrow0..wrow0+31 are wave-private)

            // ---- h^T = Wxh^T.u^T + Whh^T.h^T (+b_h, tanh) ----
            f32x4 ha[4][2];
            #pragma unroll
            for (int tn = 0; tn < 4; ++tn)
                #pragma unroll
                for (int mt = 0; mt < 2; ++mt) {
                    f32x4 a;
                    a[0]=bhf[tn][0]; a[1]=bhf[tn][1]; a[2]=bhf[tn][2]; a[3]=bhf[tn][3];
                    ha[tn][mt] = a;
                }
            #pragma unroll
            for (int kk = 0; kk < 2; ++kk) {
                short8 uf[2], hf[2];
                #pragma unroll
                for (int mt = 0; mt < 2; ++mt)
                    uf[mt] = *(const short8*)&s_u[(wrow0 + mt*16 + lm) * STR + kk*32 + q*8];
                if (d > 0) {
                    #pragma unroll
                    for (int mt = 0; mt < 2; ++mt)
                        hf[mt] = *(const short8*)&s_h[(wrow0 + mt*16 + lm) * STR + kk*32 + q*8];
                }
                #pragma unroll
                for (int tn = 0; tn < 4; ++tn)
                    #pragma unroll
                    for (int mt = 0; mt < 2; ++mt) {
                        ha[tn][mt] = __builtin_amdgcn_mfma_f32_16x16x32_bf16(
                            wxhf[tn][kk], uf[mt], ha[tn][mt], 0, 0, 0);
                        if (d > 0)
                            ha[tn][mt] = __builtin_amdgcn_mfma_f32_16x16x32_bf16(
                                whhf[tn][kk], hf[mt], ha[tn][mt], 0, 0, 0);
                    }
            }
            #pragma unroll
            for (int tn = 0; tn < 4; ++tn)
                #pragma unroll
                for (int mt = 0; mt < 2; ++mt) {
                    u32x2 p;
                    p[0] = pk2bf(tanh_fast(ha[tn][mt][0]), tanh_fast(ha[tn][mt][1]));
                    p[1] = pk2bf(tanh_fast(ha[tn][mt][2]), tanh_fast(ha[tn][mt][3]));
                    *(u32x2*)&s_h[(wrow0 + mt*16 + lm) * STR + tn*16 + q*4] = p;
                }
            // (no barrier: s_h rows are wave-private)
        }

        // ---- y = h @ Wout + bout : 2 lanes per row, fp32 Wout, fp32 store ----
        {
            int row = lane >> 1, half = lane & 1;
            const unsigned short* hr = &s_h[(wrow0 + row) * STR + half*32];
            const float* wo = Wout + half*32;
            float acc = 0.f;
            #pragma unroll
            for (int jb = 0; jb < 4; ++jb) {
                short8 hv = *(const short8*)&hr[jb*8];
                f32x4 w0 = *(const f32x4*)&wo[jb*8];
                f32x4 w1 = *(const f32x4*)&wo[jb*8 + 4];
                #pragma unroll
                for (int e = 0; e < 4; ++e)
                    acc += bf2f(hv[e]) * w0[e] + bf2f(hv[4+e]) * w1[e];
            }
            acc += __shfl_xor(acc, 1, 64);
            if (half == 0)
                out[(size_t)(tt + DLAG) * NG + G0 + wrow0 + row] = acc + boutf;
        }
        // (no barrier: next ti's writes are to this wave's own rows)
    }
}

extern "C" void kernel_launch(void* const* d_in, const int* in_sizes, int n_in,
                              void* d_out, int out_size, void* d_ws, size_t ws_size,
                              hipStream_t stream) {
    const float* x    = (const float*)d_in[0];
    const float* Win  = (const float*)d_in[1];
    const float* bin  = (const float*)d_in[2];
    const float* Wxh  = (const float*)d_in[3];
    const float* Whh  = (const float*)d_in[4];
    const float* bh   = (const float*)d_in[5];
    const float* Wout = (const float*)d_in[6];
    const float* bout = (const float*)d_in[7];
    float* out = (float*)d_out;

    dim3 grid(NG / GBLK, TOUTN / TTB);  // (16, 127)
    narx_kernel<<<grid, dim3(256), 0, stream>>>(x, Win, bin, Wxh, Whh, bh, Wout, bout, out);
}